// Round 1
// baseline (129.149 us; speedup 1.0000x reference)
//
#include <hip/hip_runtime.h>
#include <math.h>

// Problem constants
constexpr int BS = 32, NP = 64, NV = 321, PL = 12, DM = 128;
constexpr int KT = 32;   // int(64*0.5)  patches masked by time criterion
constexpr int KF = 25;   // int(64*0.4)  patches masked by freq criterion

// ---------------------------------------------------------------------------
// prep: M = W_in @ W_out (12x12), c = b_in @ W_out (12),
//       S_t = time_token * colsum(W_out), S_f = freq_token * colsum(W_out)
// layout in ws (floats): [0,144) M, [144,156) c, [156,168) S_t, [168,180) S_f
// ---------------------------------------------------------------------------
__global__ void prep_kernel(const float* __restrict__ W_in,
                            const float* __restrict__ b_in,
                            const float* __restrict__ W_out,
                            const float* __restrict__ tt,
                            const float* __restrict__ ft,
                            float* __restrict__ prep) {
  int t = threadIdx.x;
  if (t < 144) {
    int i = t / 12, l = t % 12;
    float s = 0.f;
    for (int d = 0; d < DM; ++d) s += W_in[i * DM + d] * W_out[d * PL + l];
    prep[t] = s;
  } else if (t < 156) {
    int l = t - 144;
    float cs = 0.f, cb = 0.f;
    for (int d = 0; d < DM; ++d) {
      float w = W_out[d * PL + l];
      cs += w;
      cb += b_in[d] * w;
    }
    prep[144 + l] = cb;
    prep[156 + l] = tt[0] * cs;
    prep[168 + l] = ft[0] * cs;
  }
}

// ---------------------------------------------------------------------------
// score+mask: one wave (64 lanes) per (b,v); lane p owns patch p.
// Computes cv and freq-score, ranks within the wave via LDS, ballots keep-masks.
// ---------------------------------------------------------------------------
__global__ __launch_bounds__(256) void score_mask_kernel(
    const float* __restrict__ x,
    unsigned long long* __restrict__ mT,
    unsigned long long* __restrict__ mF) {
  const int wave = threadIdx.x >> 6;
  const int p = threadIdx.x & 63;
  const int bv = blockIdx.x * 4 + wave;  // 0 .. 32*321-1 (exact multiple of 4)
  const int b = bv / NV, v = bv % NV;

  // patch base offset is a multiple of 12 floats = 48 B -> 16B aligned
  const float4* xp = (const float4*)(x + ((size_t)(b * NP + p) * NV + v) * PL);
  float4 a0 = xp[0], a1 = xp[1], a2 = xp[2];
  float xv[12] = {a0.x, a0.y, a0.z, a0.w, a1.x, a1.y, a1.z, a1.w,
                  a2.x, a2.y, a2.z, a2.w};

  // ---- coefficient of variation (std ddof=1 / (mean + 1e-6)) ----
  float s = 0.f;
#pragma unroll
  for (int i = 0; i < 12; ++i) s += xv[i];
  float m = s * (1.0f / 12.0f);
  float ss = 0.f;
#pragma unroll
  for (int i = 0; i < 12; ++i) {
    float d = xv[i] - m;
    ss += d * d;
  }
  float cv = sqrtf(ss * (1.0f / 11.0f)) / (m + 1e-6f);

  // ---- mean |rfft12| over 7 bins; angles are multiples of 30 deg ----
  const float C30[12] = {1.f, 0.86602540378443864676f, 0.5f, 0.f,
                         -0.5f, -0.86602540378443864676f, -1.f,
                         -0.86602540378443864676f, -0.5f, 0.f,
                         0.5f, 0.86602540378443864676f};
  const float S30[12] = {0.f, 0.5f, 0.86602540378443864676f, 1.f,
                         0.86602540378443864676f, 0.5f, 0.f,
                         -0.5f, -0.86602540378443864676f, -1.f,
                         -0.86602540378443864676f, -0.5f};
  float acc = 0.f;
#pragma unroll
  for (int k = 0; k < 7; ++k) {
    float re = 0.f, im = 0.f;
#pragma unroll
    for (int n = 0; n < 12; ++n) {
      int idx = (k * n) % 12;  // constant-folded (loops fully unrolled)
      re += xv[n] * C30[idx];
      im += xv[n] * S30[idx];
    }
    acc += sqrtf(re * re + im * im);
  }
  float fs = acc * (1.0f / 7.0f);

  // ---- rank within the 64 patches of this (b,v); stable tie-break by index
  __shared__ float scv[4][64];
  __shared__ float sfs[4][64];
  scv[wave][p] = cv;
  sfs[wave][p] = fs;
  __syncthreads();
  int rt = 0, rf = 0;
#pragma unroll 4
  for (int q = 0; q < 64; ++q) {
    float cq = scv[wave][q];
    rt += (cq > cv || (cq == cv && q < p)) ? 1 : 0;  // rank among largest cv
    float fq = sfs[wave][q];
    rf += (fq < fs || (fq == fs && q < p)) ? 1 : 0;  // rank among smallest fs
  }
  bool keep_t = (rt >= KT);  // top-KT cv patches get masked
  bool keep_f = (rf >= KF);  // bottom-KF score patches get masked
  unsigned long long bt = __ballot(keep_t);
  unsigned long long bf = __ballot(keep_f);
  if (p == 0) {
    mT[bv] = bt;
    mF[bv] = bf;
  }
}

// ---------------------------------------------------------------------------
// decode: one block per (b,p). x[b,p,:,:] is 321*12 = 3852 contiguous floats.
// out[l] = 0.5*((kt?E:S_t[l]) + (kf?E:S_f[l])) + b_out[l], E = x.M + c
// ---------------------------------------------------------------------------
__global__ __launch_bounds__(256) void decode_kernel(
    const float* __restrict__ x,
    const float* __restrict__ b_out,
    const float* __restrict__ prep,
    const unsigned long long* __restrict__ mT,
    const unsigned long long* __restrict__ mF,
    float* __restrict__ out) {
  const int bp = blockIdx.x;  // b*64 + p
  const int b = bp >> 6, p = bp & 63;
  __shared__ float sM[144], sc[12], sSt[12], sSf[12], sb[12];
  __shared__ float xs[NV * PL];  // 15.4 KB
  const int tid = threadIdx.x;
  if (tid < 144) sM[tid] = prep[tid];
  else if (tid < 156) sc[tid - 144] = prep[tid];
  else if (tid < 168) sSt[tid - 156] = prep[tid];
  else if (tid < 180) sSf[tid - 168] = prep[tid];
  else if (tid < 192) sb[tid - 180] = b_out[tid - 180];

  const float4* xbp = (const float4*)(x + (size_t)bp * (NV * PL));
  float4* xs4 = (float4*)xs;
  for (int i = tid; i < NV * PL / 4; i += 256) xs4[i] = xbp[i];
  __syncthreads();

  float* outp = out + (size_t)bp * (NV * PL);
  for (int e = tid; e < NV * PL; e += 256) {
    int v = e / 12, l = e - v * 12;
    float E = sc[l];
#pragma unroll
    for (int i = 0; i < 12; ++i) E += xs[v * 12 + i] * sM[i * 12 + l];
    unsigned long long mt = mT[b * NV + v];
    unsigned long long mf = mF[b * NV + v];
    bool kt = (mt >> p) & 1ull;
    bool kf = (mf >> p) & 1ull;
    float at = kt ? E : sSt[l];
    float af = kf ? E : sSf[l];
    outp[e] = 0.5f * (at + af) + sb[l];
  }
}

extern "C" void kernel_launch(void* const* d_in, const int* in_sizes, int n_in,
                              void* d_out, int out_size, void* d_ws,
                              size_t ws_size, hipStream_t stream) {
  const float* x = (const float*)d_in[0];
  const float* W_in = (const float*)d_in[1];
  const float* b_in = (const float*)d_in[2];
  const float* W_out = (const float*)d_in[3];
  const float* b_out = (const float*)d_in[4];
  const float* tt = (const float*)d_in[5];
  const float* ft = (const float*)d_in[6];
  float* out = (float*)d_out;

  float* prep = (float*)d_ws;  // 180 floats used, 1024 B reserved
  unsigned long long* mT = (unsigned long long*)((char*)d_ws + 1024);
  unsigned long long* mF = mT + BS * NV;  // total ws use ~166 KB

  hipLaunchKernelGGL(prep_kernel, dim3(1), dim3(192), 0, stream, W_in, b_in,
                     W_out, tt, ft, prep);
  hipLaunchKernelGGL(score_mask_kernel, dim3(BS * NV / 4), dim3(256), 0,
                     stream, x, mT, mF);
  hipLaunchKernelGGL(decode_kernel, dim3(BS * NP), dim3(256), 0, stream, x,
                     b_out, prep, mT, mF, out);
}